// Round 3
// baseline (438.500 us; speedup 1.0000x reference)
//
#include <hip/hip_runtime.h>
#include <math.h>

#define H_DIM 2048
#define I_DIM 5632
#define E_NUM 8
#define T_NUM 32
#define K_TOP 2
#define P_NUM 64              // total (token,expert) pairs = T*K exactly
#define GROUP 16
#define HS 8                  // h-splits in gateup
#define HCH (H_DIM / HS)      // 256
#define IS 16                 // i-splits in down
#define ICH (I_DIM / IS)      // 352
#define PNI ((size_t)P_NUM * I_DIM)
#define SWIGLU_SCALE 1.702f

// ---------------- Route: logits -> softmax -> top-2 -> compacted pair lists ----------------
__global__ __launch_bounds__(1024) void route_kernel(
    const float* __restrict__ x, const float* __restrict__ rw,
    int* __restrict__ cnt, int* __restrict__ start,
    int* __restrict__ ptok, float* __restrict__ pscale,
    int* __restrict__ tpair) {
  __shared__ float logits[T_NUM][E_NUM];
  __shared__ int   sidx[T_NUM][K_TOP];
  __shared__ float sval[T_NUM][K_TOP];
  __shared__ int   scnt[E_NUM], sstart[E_NUM];
  __shared__ int   lptok[P_NUM];
  const int tid = threadIdx.x;
  const int wave = tid >> 6, lane = tid & 63;
  // 16 waves x 16 pairs = 256 (t,e) dot products
  for (int k = 0; k < 16; ++k) {
    const int pair = wave * 16 + k;
    const int t = pair >> 3, e = pair & 7;
    float p = 0.f;
    for (int h = lane; h < H_DIM; h += 64) p += x[t * H_DIM + h] * rw[e * H_DIM + h];
    for (int off = 32; off; off >>= 1) p += __shfl_down(p, off);
    if (lane == 0) logits[t][e] = p;
  }
  __syncthreads();
  if (tid < T_NUM) {
    float m = logits[tid][0];
    for (int e = 1; e < E_NUM; ++e) m = fmaxf(m, logits[tid][e]);
    float a[E_NUM]; float s = 0.f;
    for (int e = 0; e < E_NUM; ++e) { a[e] = __expf(logits[tid][e] - m); s += a[e]; }
    const float inv = 1.f / s;
    int i1 = -1, i2 = -1; float v1 = -1.f, v2 = -1.f;
    for (int e = 0; e < E_NUM; ++e) {
      const float v = a[e] * inv;
      if (v > v1)      { v2 = v1; i2 = i1; v1 = v; i1 = e; }
      else if (v > v2) { v2 = v; i2 = e; }
    }
    sidx[tid][0] = i1; sidx[tid][1] = i2; sval[tid][0] = v1; sval[tid][1] = v2;
  }
  __syncthreads();
  if (tid < E_NUM) {
    int c = 0;
    for (int t = 0; t < T_NUM; ++t) c += (sidx[t][0] == tid) + (sidx[t][1] == tid);
    scnt[tid] = c;
  }
  __syncthreads();
  if (tid == 0) {
    int s = 0;
    for (int e = 0; e < E_NUM; ++e) { sstart[e] = s; s += scnt[e]; }
  }
  __syncthreads();
  if (tid < E_NUM) {
    cnt[tid] = scnt[tid]; start[tid] = sstart[tid];
    int p = sstart[tid];
    for (int t = 0; t < T_NUM; ++t)
      for (int s = 0; s < K_TOP; ++s)
        if (sidx[t][s] == tid) { ptok[p] = t; pscale[p] = sval[t][s]; lptok[p] = t; ++p; }
  }
  __syncthreads();
  if (tid < T_NUM) {
    int c2 = 0;
    for (int p = 0; p < P_NUM; ++p)
      if (lptok[p] == tid) { tpair[tid * K_TOP + c2] = p; ++c2; }
  }
}

// ---------------- Gate/Up partial GEMM (h-split by HS), float4 ----------------
// EPI==0: write partials pg[hs][pair][i].  EPI==1: atomicAdd into pg[pair][i].
template<int EPI>
__global__ __launch_bounds__(128, 2) void gateup_kernel(
    const float* __restrict__ x, const float* __restrict__ wg,
    const float* __restrict__ wu, const int* __restrict__ cnt,
    const int* __restrict__ start, const int* __restrict__ ptok,
    float* __restrict__ pg, float* __restrict__ pu) {
  const int e  = blockIdx.x;
  const int ic = blockIdx.y;              // 11 chunks of 512 i
  const int hs = blockIdx.z & (HS - 1);
  const int tg = blockIdx.z >> 3;
  const int c  = cnt[e];
  const int n0 = tg * GROUP;
  if (n0 >= c) return;
  const int nt = min(GROUP, c - n0);
  const int p0 = start[e] + n0;
  const int tid = threadIdx.x;
  const int h0 = hs * HCH;

  __shared__ float xs[GROUP][HCH];        // 16 KB
  for (int idx = tid; idx < GROUP * HCH; idx += 128) {
    const int j = idx >> 8, hh = idx & (HCH - 1);   // HCH == 256
    xs[j][hh] = (j < nt) ? x[ptok[p0 + j] * H_DIM + h0 + hh] : 0.f;
  }
  __syncthreads();

  const int i4 = ic * 512 + tid * 4;
  const float* wgp = wg + ((size_t)e * H_DIM + h0) * I_DIM + i4;
  const float* wup = wu + ((size_t)e * H_DIM + h0) * I_DIM + i4;

  float ag[GROUP][4], au[GROUP][4];
#pragma unroll
  for (int j = 0; j < GROUP; ++j)
#pragma unroll
    for (int q = 0; q < 4; ++q) { ag[j][q] = 0.f; au[j][q] = 0.f; }

#pragma unroll 2
  for (int hh = 0; hh < HCH; ++hh) {
    const float4 g = *(const float4*)(wgp + (size_t)hh * I_DIM);
    const float4 u = *(const float4*)(wup + (size_t)hh * I_DIM);
#pragma unroll
    for (int j = 0; j < GROUP; ++j) {
      const float xv = xs[j][hh];
      ag[j][0] = fmaf(g.x, xv, ag[j][0]);
      ag[j][1] = fmaf(g.y, xv, ag[j][1]);
      ag[j][2] = fmaf(g.z, xv, ag[j][2]);
      ag[j][3] = fmaf(g.w, xv, ag[j][3]);
      au[j][0] = fmaf(u.x, xv, au[j][0]);
      au[j][1] = fmaf(u.y, xv, au[j][1]);
      au[j][2] = fmaf(u.z, xv, au[j][2]);
      au[j][3] = fmaf(u.w, xv, au[j][3]);
    }
  }

  if (EPI == 0) {
    float* pgp = pg + (size_t)hs * PNI;
    float* pup = pu + (size_t)hs * PNI;
#pragma unroll
    for (int j = 0; j < GROUP; ++j) if (j < nt) {
      const size_t o = (size_t)(p0 + j) * I_DIM + i4;
      *(float4*)(pgp + o) = make_float4(ag[j][0], ag[j][1], ag[j][2], ag[j][3]);
      *(float4*)(pup + o) = make_float4(au[j][0], au[j][1], au[j][2], au[j][3]);
    }
  } else {
#pragma unroll
    for (int j = 0; j < GROUP; ++j) if (j < nt) {
      const size_t o = (size_t)(p0 + j) * I_DIM + i4;
#pragma unroll
      for (int q = 0; q < 4; ++q) {
        atomicAdd(&pg[o + q], ag[j][q]);
        atomicAdd(&pu[o + q], au[j][q]);
      }
    }
  }
}

// ---------------- Reduce partials + swiglu + combine-scale -> inter[pair][i] ----------------
template<int EPI>
__global__ __launch_bounds__(128) void swiglu_kernel(
    const float* __restrict__ pg, const float* __restrict__ pu,
    const float* __restrict__ pscale, float* __restrict__ inter) {
  const int p = blockIdx.x;
  const int i4 = blockIdx.y * 512 + threadIdx.x * 4;   // grid.y = 11
  const size_t off = (size_t)p * I_DIM + i4;
  float g[4] = {0.f, 0.f, 0.f, 0.f}, u[4] = {0.f, 0.f, 0.f, 0.f};
  if (EPI == 0) {
#pragma unroll
    for (int hs = 0; hs < HS; ++hs) {
      const float4 gv = *(const float4*)(pg + (size_t)hs * PNI + off);
      const float4 uv = *(const float4*)(pu + (size_t)hs * PNI + off);
      g[0] += gv.x; g[1] += gv.y; g[2] += gv.z; g[3] += gv.w;
      u[0] += uv.x; u[1] += uv.y; u[2] += uv.z; u[3] += uv.w;
    }
  } else {
    const float4 gv = *(const float4*)(pg + off);
    const float4 uv = *(const float4*)(pu + off);
    g[0] = gv.x; g[1] = gv.y; g[2] = gv.z; g[3] = gv.w;
    u[0] = uv.x; u[1] = uv.y; u[2] = uv.z; u[3] = uv.w;
  }
  const float s = pscale[p];
  float r[4];
#pragma unroll
  for (int q = 0; q < 4; ++q) {
    const float sig = 1.f / (1.f + __expf(-SWIGLU_SCALE * g[q]));
    r[q] = g[q] * sig * u[q] * s;
  }
  *(float4*)(inter + off) = make_float4(r[0], r[1], r[2], r[3]);
}

// ---------------- Down-proj partial: pout[pair][is][h] (EPI0) or atomic out (EPI1) ----------------
template<int EPI>
__global__ __launch_bounds__(128, 2) void down_kernel(
    const float* __restrict__ wd, const float* __restrict__ inter,
    const int* __restrict__ cnt, const int* __restrict__ start,
    const int* __restrict__ ptok, float* __restrict__ pout, float* __restrict__ out) {
  const int e  = blockIdx.x;
  const int hc = blockIdx.y;              // 4 chunks of 512 h
  const int is = blockIdx.z & (IS - 1);
  const int tg = blockIdx.z >> 4;
  const int c  = cnt[e];
  const int n0 = tg * GROUP;
  if (n0 >= c) return;
  const int nt = min(GROUP, c - n0);
  const int p0 = start[e] + n0;
  const int tid = threadIdx.x;
  const int i0 = is * ICH;

  __shared__ float ils[GROUP][ICH];       // 22528 B
  for (int idx = tid; idx < GROUP * ICH; idx += 128) {
    const int j = idx / ICH, ii = idx - j * ICH;
    ils[j][ii] = (j < nt) ? inter[(size_t)(p0 + j) * I_DIM + i0 + ii] : 0.f;
  }
  __syncthreads();

  const int h4 = hc * 512 + tid * 4;
  const float* wdp = wd + ((size_t)e * I_DIM + i0) * H_DIM + h4;

  float acc[GROUP][4];
#pragma unroll
  for (int j = 0; j < GROUP; ++j)
#pragma unroll
    for (int q = 0; q < 4; ++q) acc[j][q] = 0.f;

#pragma unroll 2
  for (int ii = 0; ii < ICH; ++ii) {
    const float4 w = *(const float4*)(wdp + (size_t)ii * H_DIM);
#pragma unroll
    for (int j = 0; j < GROUP; ++j) {
      const float iv = ils[j][ii];
      acc[j][0] = fmaf(w.x, iv, acc[j][0]);
      acc[j][1] = fmaf(w.y, iv, acc[j][1]);
      acc[j][2] = fmaf(w.z, iv, acc[j][2]);
      acc[j][3] = fmaf(w.w, iv, acc[j][3]);
    }
  }

  if (EPI == 0) {
#pragma unroll
    for (int j = 0; j < GROUP; ++j) if (j < nt) {
      float* pp = pout + ((size_t)(p0 + j) * IS + is) * H_DIM + h4;
      *(float4*)pp = make_float4(acc[j][0], acc[j][1], acc[j][2], acc[j][3]);
    }
  } else {
#pragma unroll
    for (int j = 0; j < GROUP; ++j) if (j < nt) {
      const int t = ptok[p0 + j];
#pragma unroll
      for (int q = 0; q < 4; ++q) atomicAdd(&out[t * H_DIM + h4 + q], acc[j][q]);
    }
  }
}

// ---------------- Final combine: out[t][h] = sum over 2 pairs x 16 is-splits ----------------
__global__ __launch_bounds__(256) void combine_kernel(
    const float* __restrict__ pout, const int* __restrict__ tpair,
    float* __restrict__ out) {
  const int t = blockIdx.x;                       // 32
  const int h4 = blockIdx.y * 1024 + threadIdx.x * 4;  // grid.y = 2
  const int pA = tpair[t * K_TOP];
  const int pB = tpair[t * K_TOP + 1];
  float s0 = 0.f, s1 = 0.f, s2 = 0.f, s3 = 0.f;
#pragma unroll
  for (int is = 0; is < IS; ++is) {
    const float4 a = *(const float4*)(pout + ((size_t)pA * IS + is) * H_DIM + h4);
    const float4 b = *(const float4*)(pout + ((size_t)pB * IS + is) * H_DIM + h4);
    s0 += a.x + b.x; s1 += a.y + b.y; s2 += a.z + b.z; s3 += a.w + b.w;
  }
  *(float4*)(out + (size_t)t * H_DIM + h4) = make_float4(s0, s1, s2, s3);
}

// ---------------- Launch ----------------
extern "C" void kernel_launch(void* const* d_in, const int* in_sizes, int n_in,
                              void* d_out, int out_size, void* d_ws, size_t ws_size,
                              hipStream_t stream) {
  const float* x  = (const float*)d_in[0];   // [32,1,2048]
  const float* rw = (const float*)d_in[1];   // [8,2048]
  const float* wg = (const float*)d_in[2];   // [8,2048,5632]
  const float* wu = (const float*)d_in[3];   // [8,2048,5632]
  const float* wd = (const float*)d_in[4];   // [8,5632,2048]
  float* out = (float*)d_out;                // [32,1,2048] f32

  float* ws     = (float*)d_ws;
  int*   cnt    = (int*)ws;                   // 8
  int*   start  = (int*)(ws + 8);             // 8
  int*   ptok   = (int*)(ws + 16);            // 64
  int*   tpair  = (int*)(ws + 80);            // 64
  float* pscale = ws + 144;                   // 64
  float* inter  = ws + 256;                   // 64*5632 = 1.44 MB
  float* pg     = inter + PNI;

  const size_t need_partial =
      (256 + PNI + 2 * (size_t)HS * PNI + (size_t)P_NUM * IS * H_DIM) * sizeof(float);
  const bool use_partial = ws_size >= need_partial;

  route_kernel<<<1, 1024, 0, stream>>>(x, rw, cnt, start, ptok, pscale, tpair);

  if (use_partial) {
    float* pu   = pg + (size_t)HS * PNI;
    float* pout = pu + (size_t)HS * PNI;
    gateup_kernel<0><<<dim3(E_NUM, 11, HS * 2), 128, 0, stream>>>(
        x, wg, wu, cnt, start, ptok, pg, pu);
    swiglu_kernel<0><<<dim3(P_NUM, 11), 128, 0, stream>>>(pg, pu, pscale, inter);
    down_kernel<0><<<dim3(E_NUM, 4, IS * 2), 128, 0, stream>>>(
        wd, inter, cnt, start, ptok, pout, out);
    combine_kernel<<<dim3(T_NUM, 2), 256, 0, stream>>>(pout, tpair, out);
  } else {
    float* pu = pg + PNI;
    hipMemsetAsync(out, 0, (size_t)out_size * sizeof(float), stream);
    hipMemsetAsync(pg, 0, 2 * PNI * sizeof(float), stream);
    gateup_kernel<1><<<dim3(E_NUM, 11, HS * 2), 128, 0, stream>>>(
        x, wg, wu, cnt, start, ptok, pg, pu);
    swiglu_kernel<1><<<dim3(P_NUM, 11), 128, 0, stream>>>(pg, pu, pscale, inter);
    down_kernel<1><<<dim3(E_NUM, 4, IS * 2), 128, 0, stream>>>(
        wd, inter, cnt, start, ptok, nullptr, out);
  }
}

// Round 4
// 433.434 us; speedup vs baseline: 1.0117x; 1.0117x over previous
//
#include <hip/hip_runtime.h>
#include <math.h>

#define H_DIM 2048
#define I_DIM 5632
#define E_NUM 8
#define T_NUM 32
#define K_TOP 2
#define P_NUM 64              // total (token,expert) pairs = T*K exactly
#define GROUP 8               // token group per block (avg cnt/expert = 8)
#define NTG 4                 // max token groups (max cnt = 32)
#define HS 8                  // h-splits in gateup
#define HCH (H_DIM / HS)      // 256
#define IS 32                 // i-splits in down
#define ICH (I_DIM / IS)      // 176
#define PNI ((size_t)P_NUM * I_DIM)
#define SWIGLU_SCALE 1.702f

// ---------------- Route: logits -> softmax -> top-2 -> compacted pair lists ----------------
__global__ __launch_bounds__(1024) void route_kernel(
    const float* __restrict__ x, const float* __restrict__ rw,
    int* __restrict__ cnt, int* __restrict__ start,
    int* __restrict__ ptok, float* __restrict__ pscale,
    int* __restrict__ tpair) {
  __shared__ float logits[T_NUM][E_NUM];
  __shared__ int   sidx[T_NUM][K_TOP];
  __shared__ float sval[T_NUM][K_TOP];
  __shared__ int   scnt[E_NUM], sstart[E_NUM];
  __shared__ int   lptok[P_NUM];
  const int tid = threadIdx.x;
  const int wave = tid >> 6, lane = tid & 63;
  // 16 waves x 16 pairs = 256 (t,e) dot products
  for (int k = 0; k < 16; ++k) {
    const int pair = wave * 16 + k;
    const int t = pair >> 3, e = pair & 7;
    float p = 0.f;
    for (int h = lane; h < H_DIM; h += 64) p += x[t * H_DIM + h] * rw[e * H_DIM + h];
    for (int off = 32; off; off >>= 1) p += __shfl_down(p, off);
    if (lane == 0) logits[t][e] = p;
  }
  __syncthreads();
  if (tid < T_NUM) {
    float m = logits[tid][0];
    for (int e = 1; e < E_NUM; ++e) m = fmaxf(m, logits[tid][e]);
    float a[E_NUM]; float s = 0.f;
    for (int e = 0; e < E_NUM; ++e) { a[e] = __expf(logits[tid][e] - m); s += a[e]; }
    const float inv = 1.f / s;
    int i1 = -1, i2 = -1; float v1 = -1.f, v2 = -1.f;
    for (int e = 0; e < E_NUM; ++e) {
      const float v = a[e] * inv;
      if (v > v1)      { v2 = v1; i2 = i1; v1 = v; i1 = e; }
      else if (v > v2) { v2 = v; i2 = e; }
    }
    sidx[tid][0] = i1; sidx[tid][1] = i2; sval[tid][0] = v1; sval[tid][1] = v2;
  }
  __syncthreads();
  if (tid < E_NUM) {
    int c = 0;
    for (int t = 0; t < T_NUM; ++t) c += (sidx[t][0] == tid) + (sidx[t][1] == tid);
    scnt[tid] = c;
  }
  __syncthreads();
  if (tid == 0) {
    int s = 0;
    for (int e = 0; e < E_NUM; ++e) { sstart[e] = s; s += scnt[e]; }
  }
  __syncthreads();
  if (tid < E_NUM) {
    cnt[tid] = scnt[tid]; start[tid] = sstart[tid];
    int p = sstart[tid];
    for (int t = 0; t < T_NUM; ++t)
      for (int s = 0; s < K_TOP; ++s)
        if (sidx[t][s] == tid) { ptok[p] = t; pscale[p] = sval[t][s]; lptok[p] = t; ++p; }
  }
  __syncthreads();
  if (tid < T_NUM) {
    int c2 = 0;
    for (int p = 0; p < P_NUM; ++p)
      if (lptok[p] == tid) { tpair[tid * K_TOP + c2] = p; ++c2; }
  }
}

// ---------------- Gate/Up partial GEMM (h-split by HS), 256 thr, float2 ----------------
// EPI==0: write partials pg[hs][pair][i].  EPI==1: atomicAdd into pg[pair][i].
template<int EPI>
__global__ __launch_bounds__(256) void gateup_kernel(
    const float* __restrict__ x, const float* __restrict__ wg,
    const float* __restrict__ wu, const int* __restrict__ cnt,
    const int* __restrict__ start, const int* __restrict__ ptok,
    float* __restrict__ pg, float* __restrict__ pu) {
  const int e  = blockIdx.x;
  const int ic = blockIdx.y;              // 11 chunks of 512 i
  const int hs = blockIdx.z & (HS - 1);
  const int tg = blockIdx.z >> 3;         // up to NTG groups of 8 tokens
  const int c  = cnt[e];
  const int n0 = tg * GROUP;
  if (n0 >= c) return;
  const int nt = min(GROUP, c - n0);
  const int p0 = start[e] + n0;
  const int tid = threadIdx.x;
  const int h0 = hs * HCH;

  __shared__ float xs[GROUP][HCH];        // 8 KB
  for (int idx = tid; idx < GROUP * HCH; idx += 256) {
    const int j = idx >> 8, hh = idx & (HCH - 1);   // HCH == 256
    xs[j][hh] = (j < nt) ? x[ptok[p0 + j] * H_DIM + h0 + hh] : 0.f;
  }
  __syncthreads();

  const int i2 = ic * 512 + tid * 2;
  const float* wgp = wg + ((size_t)e * H_DIM + h0) * I_DIM + i2;
  const float* wup = wu + ((size_t)e * H_DIM + h0) * I_DIM + i2;

  float ag[GROUP][2], au[GROUP][2];
#pragma unroll
  for (int j = 0; j < GROUP; ++j) { ag[j][0] = ag[j][1] = au[j][0] = au[j][1] = 0.f; }

#pragma unroll 4
  for (int hh = 0; hh < HCH; ++hh) {
    const float2 g = *(const float2*)(wgp + (size_t)hh * I_DIM);
    const float2 u = *(const float2*)(wup + (size_t)hh * I_DIM);
#pragma unroll
    for (int j = 0; j < GROUP; ++j) {
      const float xv = xs[j][hh];
      ag[j][0] = fmaf(g.x, xv, ag[j][0]);
      ag[j][1] = fmaf(g.y, xv, ag[j][1]);
      au[j][0] = fmaf(u.x, xv, au[j][0]);
      au[j][1] = fmaf(u.y, xv, au[j][1]);
    }
  }

  if (EPI == 0) {
    float* pgp = pg + (size_t)hs * PNI;
    float* pup = pu + (size_t)hs * PNI;
#pragma unroll
    for (int j = 0; j < GROUP; ++j) if (j < nt) {
      const size_t o = (size_t)(p0 + j) * I_DIM + i2;
      *(float2*)(pgp + o) = make_float2(ag[j][0], ag[j][1]);
      *(float2*)(pup + o) = make_float2(au[j][0], au[j][1]);
    }
  } else {
#pragma unroll
    for (int j = 0; j < GROUP; ++j) if (j < nt) {
      const size_t o = (size_t)(p0 + j) * I_DIM + i2;
      atomicAdd(&pg[o],     ag[j][0]);
      atomicAdd(&pg[o + 1], ag[j][1]);
      atomicAdd(&pu[o],     au[j][0]);
      atomicAdd(&pu[o + 1], au[j][1]);
    }
  }
}

// ---------------- Reduce partials + swiglu + combine-scale -> inter[pair][i] ----------------
template<int EPI>
__global__ __launch_bounds__(128) void swiglu_kernel(
    const float* __restrict__ pg, const float* __restrict__ pu,
    const float* __restrict__ pscale, float* __restrict__ inter) {
  const int p = blockIdx.x;
  const int i4 = blockIdx.y * 512 + threadIdx.x * 4;   // grid.y = 11
  const size_t off = (size_t)p * I_DIM + i4;
  float g[4] = {0.f, 0.f, 0.f, 0.f}, u[4] = {0.f, 0.f, 0.f, 0.f};
  if (EPI == 0) {
#pragma unroll
    for (int hs = 0; hs < HS; ++hs) {
      const float4 gv = *(const float4*)(pg + (size_t)hs * PNI + off);
      const float4 uv = *(const float4*)(pu + (size_t)hs * PNI + off);
      g[0] += gv.x; g[1] += gv.y; g[2] += gv.z; g[3] += gv.w;
      u[0] += uv.x; u[1] += uv.y; u[2] += uv.z; u[3] += uv.w;
    }
  } else {
    const float4 gv = *(const float4*)(pg + off);
    const float4 uv = *(const float4*)(pu + off);
    g[0] = gv.x; g[1] = gv.y; g[2] = gv.z; g[3] = gv.w;
    u[0] = uv.x; u[1] = uv.y; u[2] = uv.z; u[3] = uv.w;
  }
  const float s = pscale[p];
  float r[4];
#pragma unroll
  for (int q = 0; q < 4; ++q) {
    const float sig = 1.f / (1.f + __expf(-SWIGLU_SCALE * g[q]));
    r[q] = g[q] * sig * u[q] * s;
  }
  *(float4*)(inter + off) = make_float4(r[0], r[1], r[2], r[3]);
}

// ---------------- Down-proj partial: pout[pair][is][h] (EPI0) or atomic out (EPI1) ----------------
template<int EPI>
__global__ __launch_bounds__(256) void down_kernel(
    const float* __restrict__ wd, const float* __restrict__ inter,
    const int* __restrict__ cnt, const int* __restrict__ start,
    const int* __restrict__ ptok, float* __restrict__ pout, float* __restrict__ out) {
  const int e  = blockIdx.x;
  const int hc = blockIdx.y;              // 2 chunks of 1024 h
  const int is = blockIdx.z & (IS - 1);
  const int tg = blockIdx.z >> 5;         // up to NTG groups of 8 tokens
  const int c  = cnt[e];
  const int n0 = tg * GROUP;
  if (n0 >= c) return;
  const int nt = min(GROUP, c - n0);
  const int p0 = start[e] + n0;
  const int tid = threadIdx.x;
  const int i0 = is * ICH;

  __shared__ float ils[GROUP][ICH];       // 5632 B
  for (int idx = tid; idx < GROUP * ICH; idx += 256) {
    const int j = idx / ICH, ii = idx - j * ICH;
    ils[j][ii] = (j < nt) ? inter[(size_t)(p0 + j) * I_DIM + i0 + ii] : 0.f;
  }
  __syncthreads();

  const int h4 = hc * 1024 + tid * 4;
  const float* wdp = wd + ((size_t)e * I_DIM + i0) * H_DIM + h4;

  float acc[GROUP][4];
#pragma unroll
  for (int j = 0; j < GROUP; ++j)
#pragma unroll
    for (int q = 0; q < 4; ++q) acc[j][q] = 0.f;

#pragma unroll 4
  for (int ii = 0; ii < ICH; ++ii) {
    const float4 w = *(const float4*)(wdp + (size_t)ii * H_DIM);
#pragma unroll
    for (int j = 0; j < GROUP; ++j) {
      const float iv = ils[j][ii];
      acc[j][0] = fmaf(w.x, iv, acc[j][0]);
      acc[j][1] = fmaf(w.y, iv, acc[j][1]);
      acc[j][2] = fmaf(w.z, iv, acc[j][2]);
      acc[j][3] = fmaf(w.w, iv, acc[j][3]);
    }
  }

  if (EPI == 0) {
#pragma unroll
    for (int j = 0; j < GROUP; ++j) if (j < nt) {
      float* pp = pout + ((size_t)(p0 + j) * IS + is) * H_DIM + h4;
      *(float4*)pp = make_float4(acc[j][0], acc[j][1], acc[j][2], acc[j][3]);
    }
  } else {
#pragma unroll
    for (int j = 0; j < GROUP; ++j) if (j < nt) {
      const int t = ptok[p0 + j];
#pragma unroll
      for (int q = 0; q < 4; ++q) atomicAdd(&out[t * H_DIM + h4 + q], acc[j][q]);
    }
  }
}

// ---------------- Final combine: out[t][h] = sum over 2 pairs x IS is-splits ----------------
__global__ __launch_bounds__(256) void combine_kernel(
    const float* __restrict__ pout, const int* __restrict__ tpair,
    float* __restrict__ out) {
  const int t = blockIdx.x;                            // 32
  const int h4 = blockIdx.y * 1024 + threadIdx.x * 4;  // grid.y = 2
  const int pA = tpair[t * K_TOP];
  const int pB = tpair[t * K_TOP + 1];
  float s0 = 0.f, s1 = 0.f, s2 = 0.f, s3 = 0.f;
#pragma unroll
  for (int is = 0; is < IS; ++is) {
    const float4 a = *(const float4*)(pout + ((size_t)pA * IS + is) * H_DIM + h4);
    const float4 b = *(const float4*)(pout + ((size_t)pB * IS + is) * H_DIM + h4);
    s0 += a.x + b.x; s1 += a.y + b.y; s2 += a.z + b.z; s3 += a.w + b.w;
  }
  *(float4*)(out + (size_t)t * H_DIM + h4) = make_float4(s0, s1, s2, s3);
}

// ---------------- Launch ----------------
extern "C" void kernel_launch(void* const* d_in, const int* in_sizes, int n_in,
                              void* d_out, int out_size, void* d_ws, size_t ws_size,
                              hipStream_t stream) {
  const float* x  = (const float*)d_in[0];   // [32,1,2048]
  const float* rw = (const float*)d_in[1];   // [8,2048]
  const float* wg = (const float*)d_in[2];   // [8,2048,5632]
  const float* wu = (const float*)d_in[3];   // [8,2048,5632]
  const float* wd = (const float*)d_in[4];   // [8,5632,2048]
  float* out = (float*)d_out;                // [32,1,2048] f32

  float* ws     = (float*)d_ws;
  int*   cnt    = (int*)ws;                   // 8
  int*   start  = (int*)(ws + 8);             // 8
  int*   ptok   = (int*)(ws + 16);            // 64
  int*   tpair  = (int*)(ws + 80);            // 64
  float* pscale = ws + 144;                   // 64
  float* inter  = ws + 256;                   // 64*5632 = 1.44 MB
  float* pg     = inter + PNI;

  const size_t need_partial =
      (256 + PNI + 2 * (size_t)HS * PNI + (size_t)P_NUM * IS * H_DIM) * sizeof(float);
  const bool use_partial = ws_size >= need_partial;

  route_kernel<<<1, 1024, 0, stream>>>(x, rw, cnt, start, ptok, pscale, tpair);

  if (use_partial) {
    float* pu   = pg + (size_t)HS * PNI;
    float* pout = pu + (size_t)HS * PNI;
    gateup_kernel<0><<<dim3(E_NUM, 11, HS * NTG), 256, 0, stream>>>(
        x, wg, wu, cnt, start, ptok, pg, pu);
    swiglu_kernel<0><<<dim3(P_NUM, 11), 128, 0, stream>>>(pg, pu, pscale, inter);
    down_kernel<0><<<dim3(E_NUM, 2, IS * NTG), 256, 0, stream>>>(
        wd, inter, cnt, start, ptok, pout, out);
    combine_kernel<<<dim3(T_NUM, 2), 256, 0, stream>>>(pout, tpair, out);
  } else {
    float* pu = pg + PNI;
    hipMemsetAsync(out, 0, (size_t)out_size * sizeof(float), stream);
    hipMemsetAsync(pg, 0, 2 * PNI * sizeof(float), stream);
    gateup_kernel<1><<<dim3(E_NUM, 11, HS * NTG), 256, 0, stream>>>(
        x, wg, wu, cnt, start, ptok, pg, pu);
    swiglu_kernel<1><<<dim3(P_NUM, 11), 128, 0, stream>>>(pg, pu, pscale, inter);
    down_kernel<1><<<dim3(E_NUM, 2, IS * NTG), 256, 0, stream>>>(
        wd, inter, cnt, start, ptok, nullptr, out);
  }
}

// Round 5
// 374.503 us; speedup vs baseline: 1.1709x; 1.1574x over previous
//
#include <hip/hip_runtime.h>
#include <math.h>

#define H_DIM 2048
#define I_DIM 5632
#define E_NUM 8
#define T_NUM 32
#define K_TOP 2
#define P_NUM 64              // total (token,expert) pairs = T*K exactly
#define GROUP 16              // tokens per block (covers cnt<=16 in one pass)
#define NTG 2                 // token groups (cnt<=32 worst case)
#define HS 8                  // h-splits in gateup
#define HCH (H_DIM / HS)      // 256
#define IS 32                 // i-splits in down
#define ICH (I_DIM / IS)      // 176
#define PNI ((size_t)P_NUM * I_DIM)
#define SWIGLU_SCALE 1.702f

// ---------------- Route: logits -> softmax -> top-2 -> compacted pair lists ----------------
__global__ __launch_bounds__(1024) void route_kernel(
    const float* __restrict__ x, const float* __restrict__ rw,
    int* __restrict__ cnt, int* __restrict__ start,
    int* __restrict__ ptok, float* __restrict__ pscale,
    int* __restrict__ tpair) {
  __shared__ float logits[T_NUM][E_NUM];
  __shared__ int   sidx[T_NUM][K_TOP];
  __shared__ float sval[T_NUM][K_TOP];
  __shared__ int   scnt[E_NUM], sstart[E_NUM];
  __shared__ int   lptok[P_NUM];
  const int tid = threadIdx.x;
  const int wave = tid >> 6, lane = tid & 63;
  for (int k = 0; k < 16; ++k) {
    const int pair = wave * 16 + k;
    const int t = pair >> 3, e = pair & 7;
    float p = 0.f;
    for (int h = lane; h < H_DIM; h += 64) p += x[t * H_DIM + h] * rw[e * H_DIM + h];
    for (int off = 32; off; off >>= 1) p += __shfl_down(p, off);
    if (lane == 0) logits[t][e] = p;
  }
  __syncthreads();
  if (tid < T_NUM) {
    float m = logits[tid][0];
    for (int e = 1; e < E_NUM; ++e) m = fmaxf(m, logits[tid][e]);
    float a[E_NUM]; float s = 0.f;
    for (int e = 0; e < E_NUM; ++e) { a[e] = __expf(logits[tid][e] - m); s += a[e]; }
    const float inv = 1.f / s;
    int i1 = -1, i2 = -1; float v1 = -1.f, v2 = -1.f;
    for (int e = 0; e < E_NUM; ++e) {
      const float v = a[e] * inv;
      if (v > v1)      { v2 = v1; i2 = i1; v1 = v; i1 = e; }
      else if (v > v2) { v2 = v; i2 = e; }
    }
    sidx[tid][0] = i1; sidx[tid][1] = i2; sval[tid][0] = v1; sval[tid][1] = v2;
  }
  __syncthreads();
  if (tid < E_NUM) {
    int c = 0;
    for (int t = 0; t < T_NUM; ++t) c += (sidx[t][0] == tid) + (sidx[t][1] == tid);
    scnt[tid] = c;
  }
  __syncthreads();
  if (tid == 0) {
    int s = 0;
    for (int e = 0; e < E_NUM; ++e) { sstart[e] = s; s += scnt[e]; }
  }
  __syncthreads();
  if (tid < E_NUM) {
    cnt[tid] = scnt[tid]; start[tid] = sstart[tid];
    int p = sstart[tid];
    for (int t = 0; t < T_NUM; ++t)
      for (int s = 0; s < K_TOP; ++s)
        if (sidx[t][s] == tid) { ptok[p] = t; pscale[p] = sval[t][s]; lptok[p] = t; ++p; }
  }
  __syncthreads();
  if (tid < T_NUM) {
    int c2 = 0;
    for (int p = 0; p < P_NUM; ++p)
      if (lptok[p] == tid) { tpair[tid * K_TOP + c2] = p; ++c2; }
  }
}

// ---------------- Gate/Up partial GEMM (h-split by HS), b128 LDS reads ----------------
template<int EPI>
__global__ __launch_bounds__(256, 3) void gateup_kernel(
    const float* __restrict__ x, const float* __restrict__ wg,
    const float* __restrict__ wu, const int* __restrict__ cnt,
    const int* __restrict__ start, const int* __restrict__ ptok,
    float* __restrict__ pg, float* __restrict__ pu) {
  const int e  = blockIdx.x;
  const int ic = blockIdx.y;              // 11 chunks of 512 i
  const int hs = blockIdx.z & (HS - 1);
  const int tg = blockIdx.z >> 3;
  const int c  = cnt[e];
  const int n0 = tg * GROUP;
  if (n0 >= c) return;
  const int nt = min(GROUP, c - n0);
  const int p0 = start[e] + n0;
  const int tid = threadIdx.x;
  const int h0 = hs * HCH;

  __shared__ __align__(16) float xs[GROUP][HCH];   // 16 KB, row = one token
  for (int idx = tid; idx < GROUP * HCH; idx += 256) {
    const int j = idx >> 8, hh = idx & (HCH - 1);  // HCH == 256
    xs[j][hh] = (j < nt) ? x[ptok[p0 + j] * H_DIM + h0 + hh] : 0.f;
  }
  __syncthreads();

  const int i2 = ic * 512 + tid * 2;
  const float* wgp = wg + ((size_t)e * H_DIM + h0) * I_DIM + i2;
  const float* wup = wu + ((size_t)e * H_DIM + h0) * I_DIM + i2;

  float ag[GROUP][2], au[GROUP][2];
#pragma unroll
  for (int j = 0; j < GROUP; ++j) { ag[j][0] = ag[j][1] = au[j][0] = au[j][1] = 0.f; }

  for (int hh0 = 0; hh0 < HCH; hh0 += 4) {
    float2 g[4], u[4];
#pragma unroll
    for (int q = 0; q < 4; ++q) {
      g[q] = *(const float2*)(wgp + (size_t)(hh0 + q) * I_DIM);
      u[q] = *(const float2*)(wup + (size_t)(hh0 + q) * I_DIM);
    }
#pragma unroll
    for (int j = 0; j < GROUP; ++j) {
      const float4 xv = *(const float4*)&xs[j][hh0];   // ds_read_b128 broadcast
      ag[j][0] = fmaf(g[0].x, xv.x, ag[j][0]);
      ag[j][1] = fmaf(g[0].y, xv.x, ag[j][1]);
      au[j][0] = fmaf(u[0].x, xv.x, au[j][0]);
      au[j][1] = fmaf(u[0].y, xv.x, au[j][1]);
      ag[j][0] = fmaf(g[1].x, xv.y, ag[j][0]);
      ag[j][1] = fmaf(g[1].y, xv.y, ag[j][1]);
      au[j][0] = fmaf(u[1].x, xv.y, au[j][0]);
      au[j][1] = fmaf(u[1].y, xv.y, au[j][1]);
      ag[j][0] = fmaf(g[2].x, xv.z, ag[j][0]);
      ag[j][1] = fmaf(g[2].y, xv.z, ag[j][1]);
      au[j][0] = fmaf(u[2].x, xv.z, au[j][0]);
      au[j][1] = fmaf(u[2].y, xv.z, au[j][1]);
      ag[j][0] = fmaf(g[3].x, xv.w, ag[j][0]);
      ag[j][1] = fmaf(g[3].y, xv.w, ag[j][1]);
      au[j][0] = fmaf(u[3].x, xv.w, au[j][0]);
      au[j][1] = fmaf(u[3].y, xv.w, au[j][1]);
    }
  }

  if (EPI == 0) {
    float* pgp = pg + (size_t)hs * PNI;
    float* pup = pu + (size_t)hs * PNI;
#pragma unroll
    for (int j = 0; j < GROUP; ++j) if (j < nt) {
      const size_t o = (size_t)(p0 + j) * I_DIM + i2;
      *(float2*)(pgp + o) = make_float2(ag[j][0], ag[j][1]);
      *(float2*)(pup + o) = make_float2(au[j][0], au[j][1]);
    }
  } else {
#pragma unroll
    for (int j = 0; j < GROUP; ++j) if (j < nt) {
      const size_t o = (size_t)(p0 + j) * I_DIM + i2;
      atomicAdd(&pg[o],     ag[j][0]);
      atomicAdd(&pg[o + 1], ag[j][1]);
      atomicAdd(&pu[o],     au[j][0]);
      atomicAdd(&pu[o + 1], au[j][1]);
    }
  }
}

// ---------------- Reduce partials + swiglu + combine-scale -> inter[pair][i] ----------------
template<int EPI>
__global__ __launch_bounds__(128) void swiglu_kernel(
    const float* __restrict__ pg, const float* __restrict__ pu,
    const float* __restrict__ pscale, float* __restrict__ inter) {
  const int p = blockIdx.x;
  const int i4 = blockIdx.y * 512 + threadIdx.x * 4;   // grid.y = 11
  const size_t off = (size_t)p * I_DIM + i4;
  float g[4] = {0.f, 0.f, 0.f, 0.f}, u[4] = {0.f, 0.f, 0.f, 0.f};
  if (EPI == 0) {
#pragma unroll
    for (int hs = 0; hs < HS; ++hs) {
      const float4 gv = *(const float4*)(pg + (size_t)hs * PNI + off);
      const float4 uv = *(const float4*)(pu + (size_t)hs * PNI + off);
      g[0] += gv.x; g[1] += gv.y; g[2] += gv.z; g[3] += gv.w;
      u[0] += uv.x; u[1] += uv.y; u[2] += uv.z; u[3] += uv.w;
    }
  } else {
    const float4 gv = *(const float4*)(pg + off);
    const float4 uv = *(const float4*)(pu + off);
    g[0] = gv.x; g[1] = gv.y; g[2] = gv.z; g[3] = gv.w;
    u[0] = uv.x; u[1] = uv.y; u[2] = uv.z; u[3] = uv.w;
  }
  const float s = pscale[p];
  float r[4];
#pragma unroll
  for (int q = 0; q < 4; ++q) {
    const float sig = 1.f / (1.f + __expf(-SWIGLU_SCALE * g[q]));
    r[q] = g[q] * sig * u[q] * s;
  }
  *(float4*)(inter + off) = make_float4(r[0], r[1], r[2], r[3]);
}

// ---------------- Down-proj partial: pout[pair][is][h] (EPI0) or atomic out (EPI1) ----------------
template<int EPI>
__global__ __launch_bounds__(256, 4) void down_kernel(
    const float* __restrict__ wd, const float* __restrict__ inter,
    const int* __restrict__ cnt, const int* __restrict__ start,
    const int* __restrict__ ptok, float* __restrict__ pout, float* __restrict__ out) {
  const int e  = blockIdx.x;
  const int hc = blockIdx.y;              // 4 chunks of 512 h
  const int is = blockIdx.z & (IS - 1);
  const int tg = blockIdx.z >> 5;
  const int c  = cnt[e];
  const int n0 = tg * GROUP;
  if (n0 >= c) return;
  const int nt = min(GROUP, c - n0);
  const int p0 = start[e] + n0;
  const int tid = threadIdx.x;
  const int i0 = is * ICH;

  __shared__ __align__(16) float ils[GROUP][ICH];   // 11.3 KB
  for (int idx = tid; idx < GROUP * ICH; idx += 256) {
    const int j = idx / ICH, ii = idx - j * ICH;
    ils[j][ii] = (j < nt) ? inter[(size_t)(p0 + j) * I_DIM + i0 + ii] : 0.f;
  }
  __syncthreads();

  const int h2 = hc * 512 + tid * 2;
  const float* wdp = wd + ((size_t)e * I_DIM + i0) * H_DIM + h2;

  float acc[GROUP][2];
#pragma unroll
  for (int j = 0; j < GROUP; ++j) { acc[j][0] = acc[j][1] = 0.f; }

  for (int ii0 = 0; ii0 < ICH; ii0 += 4) {
    float2 w[4];
#pragma unroll
    for (int q = 0; q < 4; ++q)
      w[q] = *(const float2*)(wdp + (size_t)(ii0 + q) * H_DIM);
#pragma unroll
    for (int j = 0; j < GROUP; ++j) {
      const float4 iv = *(const float4*)&ils[j][ii0];   // ds_read_b128 broadcast
      acc[j][0] = fmaf(w[0].x, iv.x, acc[j][0]);
      acc[j][1] = fmaf(w[0].y, iv.x, acc[j][1]);
      acc[j][0] = fmaf(w[1].x, iv.y, acc[j][0]);
      acc[j][1] = fmaf(w[1].y, iv.y, acc[j][1]);
      acc[j][0] = fmaf(w[2].x, iv.z, acc[j][0]);
      acc[j][1] = fmaf(w[2].y, iv.z, acc[j][1]);
      acc[j][0] = fmaf(w[3].x, iv.w, acc[j][0]);
      acc[j][1] = fmaf(w[3].y, iv.w, acc[j][1]);
    }
  }

  if (EPI == 0) {
#pragma unroll
    for (int j = 0; j < GROUP; ++j) if (j < nt) {
      float* pp = pout + ((size_t)(p0 + j) * IS + is) * H_DIM + h2;
      *(float2*)pp = make_float2(acc[j][0], acc[j][1]);
    }
  } else {
#pragma unroll
    for (int j = 0; j < GROUP; ++j) if (j < nt) {
      const int t = ptok[p0 + j];
      atomicAdd(&out[t * H_DIM + h2],     acc[j][0]);
      atomicAdd(&out[t * H_DIM + h2 + 1], acc[j][1]);
    }
  }
}

// ---------------- Final combine: out[t][h] = sum over 2 pairs x IS is-splits ----------------
__global__ __launch_bounds__(256) void combine_kernel(
    const float* __restrict__ pout, const int* __restrict__ tpair,
    float* __restrict__ out) {
  const int t = blockIdx.x;                            // 32
  const int h4 = blockIdx.y * 1024 + threadIdx.x * 4;  // grid.y = 2
  const int pA = tpair[t * K_TOP];
  const int pB = tpair[t * K_TOP + 1];
  float s0 = 0.f, s1 = 0.f, s2 = 0.f, s3 = 0.f;
#pragma unroll
  for (int is = 0; is < IS; ++is) {
    const float4 a = *(const float4*)(pout + ((size_t)pA * IS + is) * H_DIM + h4);
    const float4 b = *(const float4*)(pout + ((size_t)pB * IS + is) * H_DIM + h4);
    s0 += a.x + b.x; s1 += a.y + b.y; s2 += a.z + b.z; s3 += a.w + b.w;
  }
  *(float4*)(out + (size_t)t * H_DIM + h4) = make_float4(s0, s1, s2, s3);
}

// ---------------- Launch ----------------
extern "C" void kernel_launch(void* const* d_in, const int* in_sizes, int n_in,
                              void* d_out, int out_size, void* d_ws, size_t ws_size,
                              hipStream_t stream) {
  const float* x  = (const float*)d_in[0];   // [32,1,2048]
  const float* rw = (const float*)d_in[1];   // [8,2048]
  const float* wg = (const float*)d_in[2];   // [8,2048,5632]
  const float* wu = (const float*)d_in[3];   // [8,2048,5632]
  const float* wd = (const float*)d_in[4];   // [8,5632,2048]
  float* out = (float*)d_out;                // [32,1,2048] f32

  float* ws     = (float*)d_ws;
  int*   cnt    = (int*)ws;                   // 8
  int*   start  = (int*)(ws + 8);             // 8
  int*   ptok   = (int*)(ws + 16);            // 64
  int*   tpair  = (int*)(ws + 80);            // 64
  float* pscale = ws + 144;                   // 64
  float* inter  = ws + 256;                   // 64*5632 = 1.44 MB
  float* pg     = inter + PNI;

  const size_t need_partial =
      (256 + PNI + 2 * (size_t)HS * PNI + (size_t)P_NUM * IS * H_DIM) * sizeof(float);
  const bool use_partial = ws_size >= need_partial;

  route_kernel<<<1, 1024, 0, stream>>>(x, rw, cnt, start, ptok, pscale, tpair);

  if (use_partial) {
    float* pu   = pg + (size_t)HS * PNI;
    float* pout = pu + (size_t)HS * PNI;
    gateup_kernel<0><<<dim3(E_NUM, 11, HS * NTG), 256, 0, stream>>>(
        x, wg, wu, cnt, start, ptok, pg, pu);
    swiglu_kernel<0><<<dim3(P_NUM, 11), 128, 0, stream>>>(pg, pu, pscale, inter);
    down_kernel<0><<<dim3(E_NUM, 4, IS * NTG), 256, 0, stream>>>(
        wd, inter, cnt, start, ptok, pout, out);
    combine_kernel<<<dim3(T_NUM, 2), 256, 0, stream>>>(pout, tpair, out);
  } else {
    float* pu = pg + PNI;
    hipMemsetAsync(out, 0, (size_t)out_size * sizeof(float), stream);
    hipMemsetAsync(pg, 0, 2 * PNI * sizeof(float), stream);
    gateup_kernel<1><<<dim3(E_NUM, 11, HS * NTG), 256, 0, stream>>>(
        x, wg, wu, cnt, start, ptok, pg, pu);
    swiglu_kernel<1><<<dim3(P_NUM, 11), 128, 0, stream>>>(pg, pu, pscale, inter);
    down_kernel<1><<<dim3(E_NUM, 4, IS * NTG), 256, 0, stream>>>(
        wd, inter, cnt, start, ptok, nullptr, out);
  }
}